// Round 1
// baseline (152.419 us; speedup 1.0000x reference)
//
#include <hip/hip_runtime.h>
#include <cstdint>
#include <cstddef>

// Problem constants
#define NB   64      // batch
#define NL   1024    // seq len
#define NA   512     // ATT_DIM
#define NE   512     // ENC_DIM (= K of the big GEMM)
#define NROWS (NB*NL)

typedef __attribute__((ext_vector_type(8))) short bf16x8;  // 8 bf16 = 4 VGPR
typedef __attribute__((ext_vector_type(4))) float f32x4;   // MFMA 16x16 acc

__device__ __forceinline__ unsigned short f2bf(float x){
    unsigned int u = __float_as_uint(x);
    u += 0x7FFFu + ((u >> 16) & 1u);      // RNE (inputs are finite)
    return (unsigned short)(u >> 16);
}

// ---------------------------------------------------------------------------
// Kernel 0: repack W_enc (fp32 [K=512][N=512]) into bf16 MFMA B-fragment order
// ws layout: [s(8 K-steps)][ks(2)][n(32 tiles)][lane(64)][8 bf16]  (16B/lane)
// B frag convention (16x16x32): lane l holds B[k = 8*(l>>4)+j][col = l&15]
// ---------------------------------------------------------------------------
__global__ __launch_bounds__(256) void k_wfrag(const float* __restrict__ Wenc,
                                               unsigned short* __restrict__ wfrag){
    const int g    = blockIdx.x * 256 + threadIdx.x;   // 0..32767
    const int lane = g & 63;
    const int n    = (g >> 6) & 31;
    const int ks   = (g >> 11) & 1;
    const int s    = g >> 12;
    const int col  = n * 16 + (lane & 15);
    const int kb   = s * 64 + ks * 32 + (lane >> 4) * 8;
    unsigned int w[4];
    #pragma unroll
    for (int p = 0; p < 4; ++p){
        unsigned short lo = f2bf(Wenc[(size_t)(kb + 2*p    ) * NA + col]);
        unsigned short hi = f2bf(Wenc[(size_t)(kb + 2*p + 1) * NA + col]);
        w[p] = (unsigned int)lo | ((unsigned int)hi << 16);
    }
    ((uint4*)wfrag)[g] = make_uint4(w[0], w[1], w[2], w[3]);
}

// ---------------------------------------------------------------------------
// Kernel 1: base[b][a] = dh[b]@W_dec[:,a] + b_dec[a] + b_enc[a] + b_cov[a]
// ---------------------------------------------------------------------------
__global__ __launch_bounds__(256) void k_base(const float* __restrict__ dh,
                                              const float* __restrict__ Wdec,
                                              const float* __restrict__ bdec,
                                              const float* __restrict__ benc,
                                              const float* __restrict__ bcov,
                                              float* __restrict__ base){
    __shared__ float h[512];
    const int b = blockIdx.x, t = threadIdx.x;
    h[t]       = dh[b*512 + t];
    h[t + 256] = dh[b*512 + t + 256];
    __syncthreads();
    #pragma unroll
    for (int rep = 0; rep < 2; ++rep){
        const int a = t + rep*256;
        float s = bdec[a] + benc[a] + bcov[a];
        #pragma unroll 4
        for (int k = 0; k < 512; ++k) s += h[k] * Wdec[k*512 + a];
        base[b*512 + a] = s;
    }
}

// ---------------------------------------------------------------------------
// Kernel 2: fused  energy[r] = relu(enc[r]@W_enc + base[b] + cov[r]*W_cov) @ W_full
// Block: 256 thr (4 waves), 64 rows, full N=512 (wave owns 128 cols), BK=64.
// ---------------------------------------------------------------------------
__global__ __launch_bounds__(256, 2) void k_energy(
        const float* __restrict__ enc,          // [65536][512]
        const float* __restrict__ cov,          // [65536]
        const float* __restrict__ base,         // [64][512]
        const unsigned short* __restrict__ wfrag,
        const float* __restrict__ Wcov,         // [512]
        const float* __restrict__ Wfull,        // [512]
        float* __restrict__ energy)             // [65536]
{
    __shared__ __align__(16) unsigned char sB[65536];  // [ks(2)][n(32)][lane][16B]
    __shared__ __align__(16) unsigned char sA[8192];   // [ks(2)][m(4)][lane][16B]
    __shared__ float sCov[64];
    __shared__ float sEp[4][64];

    const int tid  = threadIdx.x;
    const int wid  = tid >> 6, lane = tid & 63;
    const int r0   = blockIdx.x * 64;
    const int b    = r0 >> 10;

    if (tid < 64) sCov[tid] = cov[r0 + tid];

    f32x4 acc[4][8];
    #pragma unroll
    for (int m = 0; m < 4; ++m)
        #pragma unroll
        for (int n = 0; n < 8; ++n) acc[m][n] = (f32x4){0.f, 0.f, 0.f, 0.f};

    // A staging: thread t reads row rloc = t>>2, 16 floats at kloc = (t&3)*16
    const int rloc = tid >> 2, q = tid & 3;
    const float* arow = enc + (size_t)(r0 + rloc) * NE + q * 16;
    // frag write: ks = q>>1 ; first frag hi = 2*(q&1), second hi = 2*(q&1)+1
    unsigned char* aw = sA + (((q >> 1) * 4 + (rloc >> 4)) * 1024
                              + ((rloc & 15) + 32 * (q & 1)) * 16);
    const unsigned char* bsrc = (const unsigned char*)wfrag + wid * 16384 + lane * 16;
    unsigned char* bdst = sB + wid * 16384;

    for (int s = 0; s < 8; ++s){
        __syncthreads();
        // ---- stage B: 64KB of pre-packed frags, direct global->LDS
        const unsigned char* bs = bsrc + (size_t)s * 65536;
        #pragma unroll
        for (int i = 0; i < 16; ++i){
            __builtin_amdgcn_global_load_lds(
                (__attribute__((address_space(1))) void*)(bs + i * 1024),
                (__attribute__((address_space(3))) void*)(bdst + i * 1024),
                16, 0, 0);
        }
        // ---- stage A: fp32 -> bf16 fragments
        const float* ap = arow + s * 64;
        float4 v0 = *(const float4*)(ap);
        float4 v1 = *(const float4*)(ap + 4);
        float4 v2 = *(const float4*)(ap + 8);
        float4 v3 = *(const float4*)(ap + 12);
        uint4 f1, f2;
        f1.x = f2bf(v0.x) | ((unsigned)f2bf(v0.y) << 16);
        f1.y = f2bf(v0.z) | ((unsigned)f2bf(v0.w) << 16);
        f1.z = f2bf(v1.x) | ((unsigned)f2bf(v1.y) << 16);
        f1.w = f2bf(v1.z) | ((unsigned)f2bf(v1.w) << 16);
        f2.x = f2bf(v2.x) | ((unsigned)f2bf(v2.y) << 16);
        f2.y = f2bf(v2.z) | ((unsigned)f2bf(v2.w) << 16);
        f2.z = f2bf(v3.x) | ((unsigned)f2bf(v3.y) << 16);
        f2.w = f2bf(v3.z) | ((unsigned)f2bf(v3.w) << 16);
        *(uint4*)(aw)       = f1;
        *(uint4*)(aw + 256) = f2;
        __syncthreads();
        // ---- compute: 64 MFMAs / wave / step
        bf16x8 af[2][4];
        #pragma unroll
        for (int ks = 0; ks < 2; ++ks)
            #pragma unroll
            for (int m = 0; m < 4; ++m)
                af[ks][m] = *(const bf16x8*)(sA + (ks*4 + m) * 1024 + lane * 16);
        #pragma unroll
        for (int ks = 0; ks < 2; ++ks){
            #pragma unroll
            for (int n = 0; n < 8; ++n){
                bf16x8 bfr = *(const bf16x8*)(sB + (ks*32 + wid*8 + n) * 1024 + lane * 16);
                #pragma unroll
                for (int m = 0; m < 4; ++m)
                    acc[m][n] = __builtin_amdgcn_mfma_f32_16x16x32_bf16(
                                    af[ks][m], bfr, acc[m][n], 0, 0, 0);
            }
        }
    }

    // ---- epilogue: relu(acc + base + cov*Wcov) * Wfull, reduce over cols
    const int c0 = wid * 128 + (lane & 15);
    float basev[8], wcovv[8], wfullv[8];
    #pragma unroll
    for (int n = 0; n < 8; ++n){
        const int c = c0 + n * 16;
        basev[n]  = base[b * 512 + c];
        wcovv[n]  = Wcov[c];
        wfullv[n] = Wfull[c];
    }
    const int hi = lane >> 4;                 // D row = m*16 + 4*hi + reg
    float covr[4][4];
    #pragma unroll
    for (int m = 0; m < 4; ++m)
        #pragma unroll
        for (int r = 0; r < 4; ++r) covr[m][r] = sCov[m*16 + 4*hi + r];
    float epv[4][4] = {};
    #pragma unroll
    for (int m = 0; m < 4; ++m)
        #pragma unroll
        for (int n = 0; n < 8; ++n)
            #pragma unroll
            for (int r = 0; r < 4; ++r){
                float v = acc[m][n][r] + basev[n] + covr[m][r] * wcovv[n];
                v = fmaxf(v, 0.f);
                epv[m][r] += v * wfullv[n];
            }
    #pragma unroll
    for (int m = 0; m < 4; ++m)
        #pragma unroll
        for (int r = 0; r < 4; ++r){
            float v = epv[m][r];
            v += __shfl_xor(v, 1);
            v += __shfl_xor(v, 2);
            v += __shfl_xor(v, 4);
            v += __shfl_xor(v, 8);
            epv[m][r] = v;
        }
    if ((lane & 15) == 0){
        #pragma unroll
        for (int m = 0; m < 4; ++m)
            #pragma unroll
            for (int r = 0; r < 4; ++r)
                sEp[wid][m*16 + 4*hi + r] = epv[m][r];
    }
    __syncthreads();
    if (tid < 64)
        energy[r0 + tid] = sEp[0][tid] + sEp[1][tid] + sEp[2][tid] + sEp[3][tid];
}

// ---------------------------------------------------------------------------
// Kernel 3: softmax over L, alpha/new_coverage writes, weighted encoding.
// grid 64*8; block handles (b, 64-col chunk); softmax recomputed per block.
// ---------------------------------------------------------------------------
#define AWE_OFF   0
#define ALPHA_OFF 32768
#define NCOV_OFF  98304

__global__ __launch_bounds__(256) void k_finish(
        const float* __restrict__ enc, const float* __restrict__ cov,
        const float* __restrict__ energy, float* __restrict__ out)
{
    const int bid = blockIdx.x;
    const int b = bid >> 3, ec = bid & 7;
    const int tid = threadIdx.x;
    __shared__ float sa[1024];
    __shared__ float rb[16];
    __shared__ float ps[4][64];

    float4 ev = ((const float4*)(energy + b * 1024))[tid];
    float mx = fmaxf(fmaxf(ev.x, ev.y), fmaxf(ev.z, ev.w));
    #pragma unroll
    for (int off = 32; off; off >>= 1) mx = fmaxf(mx, __shfl_xor(mx, off));
    if ((tid & 63) == 0) rb[tid >> 6] = mx;
    __syncthreads();
    mx = fmaxf(fmaxf(rb[0], rb[1]), fmaxf(rb[2], rb[3]));
    float e0 = __expf(ev.x - mx), e1 = __expf(ev.y - mx),
          e2 = __expf(ev.z - mx), e3 = __expf(ev.w - mx);
    ((float4*)sa)[tid] = make_float4(e0, e1, e2, e3);
    float sm = e0 + e1 + e2 + e3;
    #pragma unroll
    for (int off = 32; off; off >>= 1) sm += __shfl_xor(sm, off);
    if ((tid & 63) == 0) rb[8 + (tid >> 6)] = sm;
    __syncthreads();
    const float inv = 1.0f / (rb[8] + rb[9] + rb[10] + rb[11]);

    if (ec == 0){
        #pragma unroll
        for (int i = 0; i < 4; ++i){
            const int idx = tid + i * 256;
            const float a = sa[idx] * inv;
            out[ALPHA_OFF + b * 1024 + idx] = a;
            out[NCOV_OFF  + b * 1024 + idx] = cov[b * 1024 + idx] + a;
        }
    }

    const int qt = tid >> 6, cl = tid & 63;
    const float* ep = enc + ((size_t)(b * 1024 + qt * 256)) * 512 + ec * 64 + cl;
    const float* w = sa + qt * 256;
    float a0 = 0.f, a1 = 0.f, a2 = 0.f, a3 = 0.f;
    for (int l = 0; l < 256; l += 4){
        a0 += ep[(size_t)(l + 0) * 512] * w[l + 0];
        a1 += ep[(size_t)(l + 1) * 512] * w[l + 1];
        a2 += ep[(size_t)(l + 2) * 512] * w[l + 2];
        a3 += ep[(size_t)(l + 3) * 512] * w[l + 3];
    }
    ps[qt][cl] = (a0 + a1) + (a2 + a3);
    __syncthreads();
    if (tid < 64)
        out[AWE_OFF + b * 512 + ec * 64 + tid] =
            (ps[0][tid] + ps[1][tid] + ps[2][tid] + ps[3][tid]) * inv;
}

// ---------------------------------------------------------------------------
extern "C" void kernel_launch(void* const* d_in, const int* in_sizes, int n_in,
                              void* d_out, int out_size, void* d_ws, size_t ws_size,
                              hipStream_t stream){
    const float* enc   = (const float*)d_in[0];
    const float* dh    = (const float*)d_in[1];
    const float* cov   = (const float*)d_in[2];
    const float* Wenc  = (const float*)d_in[3];
    const float* benc  = (const float*)d_in[4];
    const float* Wdec  = (const float*)d_in[5];
    const float* bdec  = (const float*)d_in[6];
    const float* Wcov  = (const float*)d_in[7];
    const float* bcov  = (const float*)d_in[8];
    const float* Wfull = (const float*)d_in[9];
    // d_in[10] (b_full) unused: softmax is shift-invariant.
    float* out = (float*)d_out;

    unsigned short* wfrag = (unsigned short*)d_ws;              // 512 KB
    float* base   = (float*)((char*)d_ws + 512 * 1024);        // 128 KB
    float* energy = (float*)((char*)d_ws + 640 * 1024);        // 256 KB

    k_wfrag <<<128,  256, 0, stream>>>(Wenc, wfrag);
    k_base  <<<64,   256, 0, stream>>>(dh, Wdec, bdec, benc, bcov, base);
    k_energy<<<1024, 256, 0, stream>>>(enc, cov, base, wfrag, Wcov, Wfull, energy);
    k_finish<<<512,  256, 0, stream>>>(enc, cov, energy, out);
}

// Round 2
// 85.155 us; speedup vs baseline: 1.7899x; 1.7899x over previous
//
#include <hip/hip_runtime.h>
#include <cstdint>
#include <cstddef>

// Problem constants
#define NB   64      // batch
#define NL   1024    // seq len
#define NA   512     // ATT_DIM
#define NE   512     // ENC_DIM (= K of the big GEMM)
#define NROWS (NB*NL)

typedef __attribute__((ext_vector_type(8))) short bf16x8;  // 8 bf16 = 4 VGPR
typedef __attribute__((ext_vector_type(4))) float f32x4;   // MFMA 16x16 acc

__device__ __forceinline__ unsigned short f2bf(float x){
    unsigned int u = __float_as_uint(x);
    u += 0x7FFFu + ((u >> 16) & 1u);      // RNE (inputs are finite)
    return (unsigned short)(u >> 16);
}

// ---------------------------------------------------------------------------
// Kernel 0: repack W_enc (fp32 [K=512][N=512]) into bf16 MFMA B-fragment order
// ws layout: [s(8 K-steps)][ks(2)][n(32 tiles)][lane(64)][8 bf16]  (16B/lane)
// B frag convention (16x16x32): lane l holds B[k = 8*(l>>4)+j][col = l&15]
// ---------------------------------------------------------------------------
__global__ __launch_bounds__(256) void k_wfrag(const float* __restrict__ Wenc,
                                               unsigned short* __restrict__ wfrag){
    const int g    = blockIdx.x * 256 + threadIdx.x;   // 0..32767
    const int lane = g & 63;
    const int n    = (g >> 6) & 31;
    const int ks   = (g >> 11) & 1;
    const int s    = g >> 12;
    const int col  = n * 16 + (lane & 15);
    const int kb   = s * 64 + ks * 32 + (lane >> 4) * 8;
    unsigned int w[4];
    #pragma unroll
    for (int p = 0; p < 4; ++p){
        unsigned short lo = f2bf(Wenc[(size_t)(kb + 2*p    ) * NA + col]);
        unsigned short hi = f2bf(Wenc[(size_t)(kb + 2*p + 1) * NA + col]);
        w[p] = (unsigned int)lo | ((unsigned int)hi << 16);
    }
    ((uint4*)wfrag)[g] = make_uint4(w[0], w[1], w[2], w[3]);
}

// ---------------------------------------------------------------------------
// Kernel 1: base[b][a] = dh[b]@W_dec[:,a] + b_dec[a] + b_enc[a] + b_cov[a]
// R1: latency-bound fix — 512 blocks (b x 8 a-chunks), 4 k-groups x 64 lanes,
// 4 independent accumulators, full unroll. W_dec is L2-resident (1 MB).
// ---------------------------------------------------------------------------
__global__ __launch_bounds__(256) void k_base(const float* __restrict__ dh,
                                              const float* __restrict__ Wdec,
                                              const float* __restrict__ bdec,
                                              const float* __restrict__ benc,
                                              const float* __restrict__ bcov,
                                              float* __restrict__ base){
    const int b   = blockIdx.x >> 3;
    const int a0  = (blockIdx.x & 7) * 64;
    const int tid = threadIdx.x;
    const int al  = tid & 63, kg = tid >> 6;        // 4 k-groups of 128
    __shared__ float h[512];
    __shared__ float ps[4][64];
    h[tid]       = dh[b * 512 + tid];
    h[tid + 256] = dh[b * 512 + tid + 256];
    __syncthreads();
    const float* wp = Wdec + (size_t)(kg * 128) * 512 + a0 + al;
    const float* hp = h + kg * 128;
    float s0 = 0.f, s1 = 0.f, s2 = 0.f, s3 = 0.f;
    #pragma unroll
    for (int k = 0; k < 128; k += 4){
        s0 += hp[k + 0] * wp[(size_t)(k + 0) * 512];
        s1 += hp[k + 1] * wp[(size_t)(k + 1) * 512];
        s2 += hp[k + 2] * wp[(size_t)(k + 2) * 512];
        s3 += hp[k + 3] * wp[(size_t)(k + 3) * 512];
    }
    ps[kg][al] = (s0 + s1) + (s2 + s3);
    __syncthreads();
    if (tid < 64){
        const int a = a0 + tid;
        base[b * 512 + a] = ps[0][tid] + ps[1][tid] + ps[2][tid] + ps[3][tid]
                          + bdec[a] + benc[a] + bcov[a];
    }
}

// ---------------------------------------------------------------------------
// Kernel 2: fused  energy[r] = relu(enc[r]@W_enc + base[b] + cov[r]*W_cov) @ W_full
// Block: 256 thr (4 waves), 64 rows, full N=512 (wave owns 128 cols), BK=64.
// ---------------------------------------------------------------------------
__global__ __launch_bounds__(256, 2) void k_energy(
        const float* __restrict__ enc,          // [65536][512]
        const float* __restrict__ cov,          // [65536]
        const float* __restrict__ base,         // [64][512]
        const unsigned short* __restrict__ wfrag,
        const float* __restrict__ Wcov,         // [512]
        const float* __restrict__ Wfull,        // [512]
        float* __restrict__ energy)             // [65536]
{
    __shared__ __align__(16) unsigned char sB[65536];  // [ks(2)][n(32)][lane][16B]
    __shared__ __align__(16) unsigned char sA[8192];   // [ks(2)][m(4)][lane][16B]
    __shared__ float sCov[64];
    __shared__ float sEp[4][64];

    const int tid  = threadIdx.x;
    const int wid  = tid >> 6, lane = tid & 63;
    const int r0   = blockIdx.x * 64;
    const int b    = r0 >> 10;

    if (tid < 64) sCov[tid] = cov[r0 + tid];

    f32x4 acc[4][8];
    #pragma unroll
    for (int m = 0; m < 4; ++m)
        #pragma unroll
        for (int n = 0; n < 8; ++n) acc[m][n] = (f32x4){0.f, 0.f, 0.f, 0.f};

    // A staging: thread t reads row rloc = t>>2, 16 floats at kloc = (t&3)*16
    const int rloc = tid >> 2, q = tid & 3;
    const float* arow = enc + (size_t)(r0 + rloc) * NE + q * 16;
    // frag write: ks = q>>1 ; first frag hi = 2*(q&1), second hi = 2*(q&1)+1
    unsigned char* aw = sA + (((q >> 1) * 4 + (rloc >> 4)) * 1024
                              + ((rloc & 15) + 32 * (q & 1)) * 16);
    const unsigned char* bsrc = (const unsigned char*)wfrag + wid * 16384 + lane * 16;
    unsigned char* bdst = sB + wid * 16384;

    for (int s = 0; s < 8; ++s){
        __syncthreads();
        // ---- stage B: 64KB of pre-packed frags, direct global->LDS
        const unsigned char* bs = bsrc + (size_t)s * 65536;
        #pragma unroll
        for (int i = 0; i < 16; ++i){
            __builtin_amdgcn_global_load_lds(
                (__attribute__((address_space(1))) void*)(bs + i * 1024),
                (__attribute__((address_space(3))) void*)(bdst + i * 1024),
                16, 0, 0);
        }
        // ---- stage A: fp32 -> bf16 fragments
        const float* ap = arow + s * 64;
        float4 v0 = *(const float4*)(ap);
        float4 v1 = *(const float4*)(ap + 4);
        float4 v2 = *(const float4*)(ap + 8);
        float4 v3 = *(const float4*)(ap + 12);
        uint4 f1, f2;
        f1.x = f2bf(v0.x) | ((unsigned)f2bf(v0.y) << 16);
        f1.y = f2bf(v0.z) | ((unsigned)f2bf(v0.w) << 16);
        f1.z = f2bf(v1.x) | ((unsigned)f2bf(v1.y) << 16);
        f1.w = f2bf(v1.z) | ((unsigned)f2bf(v1.w) << 16);
        f2.x = f2bf(v2.x) | ((unsigned)f2bf(v2.y) << 16);
        f2.y = f2bf(v2.z) | ((unsigned)f2bf(v2.w) << 16);
        f2.z = f2bf(v3.x) | ((unsigned)f2bf(v3.y) << 16);
        f2.w = f2bf(v3.z) | ((unsigned)f2bf(v3.w) << 16);
        *(uint4*)(aw)       = f1;
        *(uint4*)(aw + 256) = f2;
        __syncthreads();
        // ---- compute: 64 MFMAs / wave / step
        bf16x8 af[2][4];
        #pragma unroll
        for (int ks = 0; ks < 2; ++ks)
            #pragma unroll
            for (int m = 0; m < 4; ++m)
                af[ks][m] = *(const bf16x8*)(sA + (ks*4 + m) * 1024 + lane * 16);
        #pragma unroll
        for (int ks = 0; ks < 2; ++ks){
            #pragma unroll
            for (int n = 0; n < 8; ++n){
                bf16x8 bfr = *(const bf16x8*)(sB + (ks*32 + wid*8 + n) * 1024 + lane * 16);
                #pragma unroll
                for (int m = 0; m < 4; ++m)
                    acc[m][n] = __builtin_amdgcn_mfma_f32_16x16x32_bf16(
                                    af[ks][m], bfr, acc[m][n], 0, 0, 0);
            }
        }
    }

    // ---- epilogue: relu(acc + base + cov*Wcov) * Wfull, reduce over cols
    const int c0 = wid * 128 + (lane & 15);
    float basev[8], wcovv[8], wfullv[8];
    #pragma unroll
    for (int n = 0; n < 8; ++n){
        const int c = c0 + n * 16;
        basev[n]  = base[b * 512 + c];
        wcovv[n]  = Wcov[c];
        wfullv[n] = Wfull[c];
    }
    const int hi = lane >> 4;                 // D row = m*16 + 4*hi + reg
    float covr[4][4];
    #pragma unroll
    for (int m = 0; m < 4; ++m)
        #pragma unroll
        for (int r = 0; r < 4; ++r) covr[m][r] = sCov[m*16 + 4*hi + r];
    float epv[4][4] = {};
    #pragma unroll
    for (int m = 0; m < 4; ++m)
        #pragma unroll
        for (int n = 0; n < 8; ++n)
            #pragma unroll
            for (int r = 0; r < 4; ++r){
                float v = acc[m][n][r] + basev[n] + covr[m][r] * wcovv[n];
                v = fmaxf(v, 0.f);
                epv[m][r] += v * wfullv[n];
            }
    #pragma unroll
    for (int m = 0; m < 4; ++m)
        #pragma unroll
        for (int r = 0; r < 4; ++r){
            float v = epv[m][r];
            v += __shfl_xor(v, 1);
            v += __shfl_xor(v, 2);
            v += __shfl_xor(v, 4);
            v += __shfl_xor(v, 8);
            epv[m][r] = v;
        }
    if ((lane & 15) == 0){
        #pragma unroll
        for (int m = 0; m < 4; ++m)
            #pragma unroll
            for (int r = 0; r < 4; ++r)
                sEp[wid][m*16 + 4*hi + r] = epv[m][r];
    }
    __syncthreads();
    if (tid < 64)
        energy[r0 + tid] = sEp[0][tid] + sEp[1][tid] + sEp[2][tid] + sEp[3][tid];
}

// ---------------------------------------------------------------------------
// Kernel 3: softmax over L, alpha/new_coverage writes, weighted encoding.
// grid 64*8; block handles (b, 64-col chunk); softmax recomputed per block.
// ---------------------------------------------------------------------------
#define AWE_OFF   0
#define ALPHA_OFF 32768
#define NCOV_OFF  98304

__global__ __launch_bounds__(256) void k_finish(
        const float* __restrict__ enc, const float* __restrict__ cov,
        const float* __restrict__ energy, float* __restrict__ out)
{
    const int bid = blockIdx.x;
    const int b = bid >> 3, ec = bid & 7;
    const int tid = threadIdx.x;
    __shared__ float sa[1024];
    __shared__ float rb[16];
    __shared__ float ps[4][64];

    float4 ev = ((const float4*)(energy + b * 1024))[tid];
    float mx = fmaxf(fmaxf(ev.x, ev.y), fmaxf(ev.z, ev.w));
    #pragma unroll
    for (int off = 32; off; off >>= 1) mx = fmaxf(mx, __shfl_xor(mx, off));
    if ((tid & 63) == 0) rb[tid >> 6] = mx;
    __syncthreads();
    mx = fmaxf(fmaxf(rb[0], rb[1]), fmaxf(rb[2], rb[3]));
    float e0 = __expf(ev.x - mx), e1 = __expf(ev.y - mx),
          e2 = __expf(ev.z - mx), e3 = __expf(ev.w - mx);
    ((float4*)sa)[tid] = make_float4(e0, e1, e2, e3);
    float sm = e0 + e1 + e2 + e3;
    #pragma unroll
    for (int off = 32; off; off >>= 1) sm += __shfl_xor(sm, off);
    if ((tid & 63) == 0) rb[8 + (tid >> 6)] = sm;
    __syncthreads();
    const float inv = 1.0f / (rb[8] + rb[9] + rb[10] + rb[11]);

    if (ec == 0){
        #pragma unroll
        for (int i = 0; i < 4; ++i){
            const int idx = tid + i * 256;
            const float a = sa[idx] * inv;
            out[ALPHA_OFF + b * 1024 + idx] = a;
            out[NCOV_OFF  + b * 1024 + idx] = cov[b * 1024 + idx] + a;
        }
    }

    const int qt = tid >> 6, cl = tid & 63;
    const float* ep = enc + ((size_t)(b * 1024 + qt * 256)) * 512 + ec * 64 + cl;
    const float* w = sa + qt * 256;
    float a0 = 0.f, a1 = 0.f, a2 = 0.f, a3 = 0.f;
    for (int l = 0; l < 256; l += 4){
        a0 += ep[(size_t)(l + 0) * 512] * w[l + 0];
        a1 += ep[(size_t)(l + 1) * 512] * w[l + 1];
        a2 += ep[(size_t)(l + 2) * 512] * w[l + 2];
        a3 += ep[(size_t)(l + 3) * 512] * w[l + 3];
    }
    ps[qt][cl] = (a0 + a1) + (a2 + a3);
    __syncthreads();
    if (tid < 64)
        out[AWE_OFF + b * 512 + ec * 64 + tid] =
            (ps[0][tid] + ps[1][tid] + ps[2][tid] + ps[3][tid]) * inv;
}

// ---------------------------------------------------------------------------
extern "C" void kernel_launch(void* const* d_in, const int* in_sizes, int n_in,
                              void* d_out, int out_size, void* d_ws, size_t ws_size,
                              hipStream_t stream){
    const float* enc   = (const float*)d_in[0];
    const float* dh    = (const float*)d_in[1];
    const float* cov   = (const float*)d_in[2];
    const float* Wenc  = (const float*)d_in[3];
    const float* benc  = (const float*)d_in[4];
    const float* Wdec  = (const float*)d_in[5];
    const float* bdec  = (const float*)d_in[6];
    const float* Wcov  = (const float*)d_in[7];
    const float* bcov  = (const float*)d_in[8];
    const float* Wfull = (const float*)d_in[9];
    // d_in[10] (b_full) unused: softmax is shift-invariant.
    float* out = (float*)d_out;

    unsigned short* wfrag = (unsigned short*)d_ws;              // 512 KB
    float* base   = (float*)((char*)d_ws + 512 * 1024);        // 128 KB
    float* energy = (float*)((char*)d_ws + 640 * 1024);        // 256 KB

    k_wfrag <<<128,  256, 0, stream>>>(Wenc, wfrag);
    k_base  <<<512,  256, 0, stream>>>(dh, Wdec, bdec, benc, bcov, base);
    k_energy<<<1024, 256, 0, stream>>>(enc, cov, base, wfrag, Wcov, Wfull, energy);
    k_finish<<<512,  256, 0, stream>>>(enc, cov, energy, out);
}

// Round 3
// 78.014 us; speedup vs baseline: 1.9537x; 1.0915x over previous
//
#include <hip/hip_runtime.h>
#include <cstdint>
#include <cstddef>

// Problem constants
#define NB   64      // batch
#define NL   1024    // seq len
#define NA   512     // ATT_DIM
#define NE   512     // ENC_DIM (= K of the big GEMM)

typedef __attribute__((ext_vector_type(8))) short bf16x8;  // 8 bf16 = 4 VGPR
typedef __attribute__((ext_vector_type(4))) float f32x4;   // MFMA 16x16 acc

__device__ __forceinline__ unsigned short f2bf(float x){
    unsigned int u = __float_as_uint(x);
    u += 0x7FFFu + ((u >> 16) & 1u);      // RNE (inputs are finite)
    return (unsigned short)(u >> 16);
}

// ---------------------------------------------------------------------------
// Kernel 0: repack W_enc (fp32 [K=512][N=512]) into bf16 MFMA B-fragment order,
// grouped per (step s, col-wave cw) so each wave's per-step B is contiguous.
// chunk id = ((s*8 + cw)*2 + ks)*4 + n ; element = chunk*64 + lane (16B each)
// Chunk lane l holds B[k = 64s+32ks+8*(l>>4)+j][col = 64cw+16n+(l&15)], j=0..7
// ---------------------------------------------------------------------------
__global__ __launch_bounds__(256) void k_wfrag(const float* __restrict__ Wenc,
                                               unsigned short* __restrict__ wfrag){
    const int g    = blockIdx.x * 256 + threadIdx.x;   // 0..32767
    const int lane = g & 63;
    const int n    = (g >> 6) & 3;
    const int ks   = (g >> 8) & 1;
    const int cw   = (g >> 9) & 7;
    const int s    = g >> 12;
    const int col  = cw * 64 + n * 16 + (lane & 15);
    const int kb   = s * 64 + ks * 32 + (lane >> 4) * 8;
    unsigned int w[4];
    #pragma unroll
    for (int p = 0; p < 4; ++p){
        unsigned short lo = f2bf(Wenc[(size_t)(kb + 2*p    ) * NA + col]);
        unsigned short hi = f2bf(Wenc[(size_t)(kb + 2*p + 1) * NA + col]);
        w[p] = (unsigned int)lo | ((unsigned int)hi << 16);
    }
    ((uint4*)wfrag)[g] = make_uint4(w[0], w[1], w[2], w[3]);
}

// ---------------------------------------------------------------------------
// Kernel 1: base[b][a] = dh[b]@W_dec[:,a] + b_dec[a] + b_enc[a] + b_cov[a]
// ---------------------------------------------------------------------------
__global__ __launch_bounds__(256) void k_base(const float* __restrict__ dh,
                                              const float* __restrict__ Wdec,
                                              const float* __restrict__ bdec,
                                              const float* __restrict__ benc,
                                              const float* __restrict__ bcov,
                                              float* __restrict__ base){
    const int b   = blockIdx.x >> 3;
    const int a0  = (blockIdx.x & 7) * 64;
    const int tid = threadIdx.x;
    const int al  = tid & 63, kg = tid >> 6;        // 4 k-groups of 128
    __shared__ float h[512];
    __shared__ float ps[4][64];
    h[tid]       = dh[b * 512 + tid];
    h[tid + 256] = dh[b * 512 + tid + 256];
    __syncthreads();
    const float* wp = Wdec + (size_t)(kg * 128) * 512 + a0 + al;
    const float* hp = h + kg * 128;
    float s0 = 0.f, s1 = 0.f, s2 = 0.f, s3 = 0.f;
    #pragma unroll
    for (int k = 0; k < 128; k += 4){
        s0 += hp[k + 0] * wp[(size_t)(k + 0) * 512];
        s1 += hp[k + 1] * wp[(size_t)(k + 1) * 512];
        s2 += hp[k + 2] * wp[(size_t)(k + 2) * 512];
        s3 += hp[k + 3] * wp[(size_t)(k + 3) * 512];
    }
    ps[kg][al] = (s0 + s1) + (s2 + s3);
    __syncthreads();
    if (tid < 64){
        const int a = a0 + tid;
        base[b * 512 + a] = ps[0][tid] + ps[1][tid] + ps[2][tid] + ps[3][tid]
                          + bdec[a] + benc[a] + bcov[a];
    }
}

// ---------------------------------------------------------------------------
// Kernel 2: energy[r] = relu(enc[r]@W_enc + base[b] + cov[r]*W_cov) @ W_full
// R2: BM=128, 512 thr / 8 waves; wave = col-slice (128r x 64c, col-disjoint).
// B: global->reg, wave-private, reg-double-buffered (no LDS, no barrier).
// A: LDS double-buffered, ONE barrier per K-step; loads issued pre-MFMA,
// convert+ds_write post-MFMA so the HBM latency hides under the MFMA cluster.
// ---------------------------------------------------------------------------
__global__ __launch_bounds__(512, 2) void k_energy(
        const float* __restrict__ enc,          // [65536][512]
        const float* __restrict__ cov,          // [65536]
        const float* __restrict__ base,         // [64][512]
        const unsigned short* __restrict__ wfrag,
        const float* __restrict__ Wcov,         // [512]
        const float* __restrict__ Wfull,        // [512]
        float* __restrict__ energy)             // [65536]
{
    __shared__ __align__(16) unsigned char sA[2][16384]; // [ks(2)][m(8)][lane][16B]
    __shared__ float sEp[8][128];
    __shared__ float sCov[128];

    const int tid  = threadIdx.x;
    const int wid  = tid >> 6, lane = tid & 63;
    const int r0   = blockIdx.x * 128;
    const int b    = r0 >> 10;

    if (tid < 128) sCov[tid] = cov[r0 + tid];

    // A staging: thread t covers row rloc=t>>2, 16 floats at q*16 within step
    const int rloc = tid >> 2, q = tid & 3;
    const float* arow = enc + (size_t)(r0 + rloc) * NE + q * 16;
    const int awoff = ((q >> 1) * 8 + (rloc >> 4)) * 1024
                    + ((rloc & 15) + 32 * (q & 1)) * 16;

    // B: wave-private fragment stream. element idx = s*4096 + wid*512 + j*64 + lane
    const bf16x8* bbase = (const bf16x8*)wfrag + wid * 512 + lane;

    f32x4 acc[8][4];
    #pragma unroll
    for (int m = 0; m < 8; ++m)
        #pragma unroll
        for (int n = 0; n < 4; ++n) acc[m][n] = (f32x4){0.f, 0.f, 0.f, 0.f};

    // ---- prologue: B(0) to regs, A(0) to sA[0]
    bf16x8 bcur[8], bnxt[8];
    #pragma unroll
    for (int j = 0; j < 8; ++j) bcur[j] = bbase[j * 64];
    {
        float4 v0 = *(const float4*)(arow);
        float4 v1 = *(const float4*)(arow + 4);
        float4 v2 = *(const float4*)(arow + 8);
        float4 v3 = *(const float4*)(arow + 12);
        uint4 f1, f2;
        f1.x = f2bf(v0.x) | ((unsigned)f2bf(v0.y) << 16);
        f1.y = f2bf(v0.z) | ((unsigned)f2bf(v0.w) << 16);
        f1.z = f2bf(v1.x) | ((unsigned)f2bf(v1.y) << 16);
        f1.w = f2bf(v1.z) | ((unsigned)f2bf(v1.w) << 16);
        f2.x = f2bf(v2.x) | ((unsigned)f2bf(v2.y) << 16);
        f2.y = f2bf(v2.z) | ((unsigned)f2bf(v2.w) << 16);
        f2.z = f2bf(v3.x) | ((unsigned)f2bf(v3.y) << 16);
        f2.w = f2bf(v3.z) | ((unsigned)f2bf(v3.w) << 16);
        *(uint4*)(sA[0] + awoff)       = f1;
        *(uint4*)(sA[0] + awoff + 256) = f2;
    }
    __syncthreads();

    #pragma unroll
    for (int s = 0; s < 8; ++s){
        const int cb = s & 1;
        // issue next A global loads (HBM) and next B loads (L2) EARLY
        float4 av0, av1, av2, av3;
        if (s < 7){
            const float* ap = arow + (s + 1) * 64;
            av0 = *(const float4*)(ap);
            av1 = *(const float4*)(ap + 4);
            av2 = *(const float4*)(ap + 8);
            av3 = *(const float4*)(ap + 12);
            const bf16x8* bp = bbase + (s + 1) * 4096;
            #pragma unroll
            for (int j = 0; j < 8; ++j) bnxt[j] = bp[j * 64];
        }
        // compute: 64 MFMAs/wave on sA[cb] x bcur
        #pragma unroll
        for (int ks = 0; ks < 2; ++ks){
            bf16x8 af[8];
            #pragma unroll
            for (int m = 0; m < 8; ++m)
                af[m] = *(const bf16x8*)(sA[cb] + (ks * 8 + m) * 1024 + lane * 16);
            #pragma unroll
            for (int n = 0; n < 4; ++n)
                #pragma unroll
                for (int m = 0; m < 8; ++m)
                    acc[m][n] = __builtin_amdgcn_mfma_f32_16x16x32_bf16(
                                    af[m], bcur[ks * 4 + n], acc[m][n], 0, 0, 0);
        }
        // convert + store next A tile into the other buffer
        if (s < 7){
            uint4 f1, f2;
            f1.x = f2bf(av0.x) | ((unsigned)f2bf(av0.y) << 16);
            f1.y = f2bf(av0.z) | ((unsigned)f2bf(av0.w) << 16);
            f1.z = f2bf(av1.x) | ((unsigned)f2bf(av1.y) << 16);
            f1.w = f2bf(av1.z) | ((unsigned)f2bf(av1.w) << 16);
            f2.x = f2bf(av2.x) | ((unsigned)f2bf(av2.y) << 16);
            f2.y = f2bf(av2.z) | ((unsigned)f2bf(av2.w) << 16);
            f2.z = f2bf(av3.x) | ((unsigned)f2bf(av3.y) << 16);
            f2.w = f2bf(av3.z) | ((unsigned)f2bf(av3.w) << 16);
            *(uint4*)(sA[cb ^ 1] + awoff)       = f1;
            *(uint4*)(sA[cb ^ 1] + awoff + 256) = f2;
            #pragma unroll
            for (int j = 0; j < 8; ++j) bcur[j] = bnxt[j];
        }
        __syncthreads();
    }

    // ---- epilogue: relu(acc + base + cov*Wcov) * Wfull, reduce over cols
    const int c0 = wid * 64 + (lane & 15);
    float basev[4], wcovv[4], wfullv[4];
    #pragma unroll
    for (int n = 0; n < 4; ++n){
        const int c = c0 + n * 16;
        basev[n]  = base[b * 512 + c];
        wcovv[n]  = Wcov[c];
        wfullv[n] = Wfull[c];
    }
    const int hi = lane >> 4;                 // D row = m*16 + 4*hi + reg
    float epv[8][4];
    #pragma unroll
    for (int m = 0; m < 8; ++m){
        #pragma unroll
        for (int r = 0; r < 4; ++r){
            const float cv = sCov[m * 16 + 4 * hi + r];
            float e = 0.f;
            #pragma unroll
            for (int n = 0; n < 4; ++n){
                float v = acc[m][n][r] + basev[n] + cv * wcovv[n];
                v = fmaxf(v, 0.f);
                e += v * wfullv[n];
            }
            epv[m][r] = e;
        }
    }
    #pragma unroll
    for (int m = 0; m < 8; ++m)
        #pragma unroll
        for (int r = 0; r < 4; ++r){
            float v = epv[m][r];
            v += __shfl_xor(v, 1);
            v += __shfl_xor(v, 2);
            v += __shfl_xor(v, 4);
            v += __shfl_xor(v, 8);
            epv[m][r] = v;
        }
    if ((lane & 15) == 0){
        #pragma unroll
        for (int m = 0; m < 8; ++m)
            #pragma unroll
            for (int r = 0; r < 4; ++r)
                sEp[wid][m * 16 + 4 * hi + r] = epv[m][r];
    }
    __syncthreads();
    if (tid < 128)
        energy[r0 + tid] = ((sEp[0][tid] + sEp[1][tid]) + (sEp[2][tid] + sEp[3][tid]))
                         + ((sEp[4][tid] + sEp[5][tid]) + (sEp[6][tid] + sEp[7][tid]));
}

// ---------------------------------------------------------------------------
// Kernel 3: softmax over L, alpha/new_coverage writes, weighted encoding.
// ---------------------------------------------------------------------------
#define AWE_OFF   0
#define ALPHA_OFF 32768
#define NCOV_OFF  98304

__global__ __launch_bounds__(256) void k_finish(
        const float* __restrict__ enc, const float* __restrict__ cov,
        const float* __restrict__ energy, float* __restrict__ out)
{
    const int bid = blockIdx.x;
    const int b = bid >> 3, ec = bid & 7;
    const int tid = threadIdx.x;
    __shared__ float sa[1024];
    __shared__ float rb[16];
    __shared__ float ps[4][64];

    float4 ev = ((const float4*)(energy + b * 1024))[tid];
    float mx = fmaxf(fmaxf(ev.x, ev.y), fmaxf(ev.z, ev.w));
    #pragma unroll
    for (int off = 32; off; off >>= 1) mx = fmaxf(mx, __shfl_xor(mx, off));
    if ((tid & 63) == 0) rb[tid >> 6] = mx;
    __syncthreads();
    mx = fmaxf(fmaxf(rb[0], rb[1]), fmaxf(rb[2], rb[3]));
    float e0 = __expf(ev.x - mx), e1 = __expf(ev.y - mx),
          e2 = __expf(ev.z - mx), e3 = __expf(ev.w - mx);
    ((float4*)sa)[tid] = make_float4(e0, e1, e2, e3);
    float sm = e0 + e1 + e2 + e3;
    #pragma unroll
    for (int off = 32; off; off >>= 1) sm += __shfl_xor(sm, off);
    if ((tid & 63) == 0) rb[8 + (tid >> 6)] = sm;
    __syncthreads();
    const float inv = 1.0f / (rb[8] + rb[9] + rb[10] + rb[11]);

    if (ec == 0){
        #pragma unroll
        for (int i = 0; i < 4; ++i){
            const int idx = tid + i * 256;
            const float a = sa[idx] * inv;
            out[ALPHA_OFF + b * 1024 + idx] = a;
            out[NCOV_OFF  + b * 1024 + idx] = cov[b * 1024 + idx] + a;
        }
    }

    const int qt = tid >> 6, cl = tid & 63;
    const float* ep = enc + ((size_t)(b * 1024 + qt * 256)) * 512 + ec * 64 + cl;
    const float* w = sa + qt * 256;
    float a0 = 0.f, a1 = 0.f, a2 = 0.f, a3 = 0.f;
    for (int l = 0; l < 256; l += 4){
        a0 += ep[(size_t)(l + 0) * 512] * w[l + 0];
        a1 += ep[(size_t)(l + 1) * 512] * w[l + 1];
        a2 += ep[(size_t)(l + 2) * 512] * w[l + 2];
        a3 += ep[(size_t)(l + 3) * 512] * w[l + 3];
    }
    ps[qt][cl] = (a0 + a1) + (a2 + a3);
    __syncthreads();
    if (tid < 64)
        out[AWE_OFF + b * 512 + ec * 64 + tid] =
            (ps[0][tid] + ps[1][tid] + ps[2][tid] + ps[3][tid]) * inv;
}

// ---------------------------------------------------------------------------
extern "C" void kernel_launch(void* const* d_in, const int* in_sizes, int n_in,
                              void* d_out, int out_size, void* d_ws, size_t ws_size,
                              hipStream_t stream){
    const float* enc   = (const float*)d_in[0];
    const float* dh    = (const float*)d_in[1];
    const float* cov   = (const float*)d_in[2];
    const float* Wenc  = (const float*)d_in[3];
    const float* benc  = (const float*)d_in[4];
    const float* Wdec  = (const float*)d_in[5];
    const float* bdec  = (const float*)d_in[6];
    const float* Wcov  = (const float*)d_in[7];
    const float* bcov  = (const float*)d_in[8];
    const float* Wfull = (const float*)d_in[9];
    // d_in[10] (b_full) unused: softmax is shift-invariant.
    float* out = (float*)d_out;

    unsigned short* wfrag = (unsigned short*)d_ws;              // 512 KB
    float* base   = (float*)((char*)d_ws + 512 * 1024);        // 128 KB
    float* energy = (float*)((char*)d_ws + 640 * 1024);        // 256 KB

    k_wfrag <<<128,  256, 0, stream>>>(Wenc, wfrag);
    k_base  <<<512,  256, 0, stream>>>(dh, Wdec, bdec, benc, bcov, base);
    k_energy<<<512,  512, 0, stream>>>(enc, cov, base, wfrag, Wcov, Wfull, energy);
    k_finish<<<512,  256, 0, stream>>>(enc, cov, energy, out);
}